// Round 20
// baseline (80.412 us; speedup 1.0000x reference)
//
#include <hip/hip_runtime.h>

// MPS classifier: logits[b,o] = (v/||v||)·cls[o] + log||v||,
//   v = head0(b) · M_1(b) · ... · M_783(b),  M_n = A_n + x[b,n]*(B_n - A_n).
// Chain associative; normalizations telescope.
//
// K1 (chunk_kernel, r13/r19 source): f16 chain (v_pk_fma_f16 on raw
//   `unsigned` f16x2 bit patterns), 2 lanes/sample, [5][5] arrays, L=8
//   (C=98), launch_bounds(256,4). Allocation is erratic across
//   co-compilations (VGPR 32-56, 40-49us) -- accepted.
// K2 (combine_kernel): depth-15 DMA ring on 16 LDS slots + 2-stage SW
//   pipeline. r19's depth-7 ring stalled at C=98: 7 x ~310cy in flight
//   < ~2000cy loaded-HBM latency. 15-deep covers ~4500cy -> per-chunk
//   cost falls to the compute chain (~225cy). Slot reuse keeps the
//   2-iteration gap invariant (r17 race fix). Counted vmcnt(13);
//   conservative vmcnt(0) tail. lbuf pre-summed before staging.

constexpr int Bsz = 2048;
constexpr int Nn  = 784;
constexpr int NS  = 783;
constexpr int LCH = 8;      // sites per chunk
constexpr int NCH = (NS + LCH - 1) / LCH;   // 98 chunks

// packed-f16 VOP3P on raw i32 registers (semantics proven r9-r19).
#define PKH_FMA(d, a, b, c) \
  asm("v_pk_fma_f16 %0, %1, %2, %3" : "=v"(d) : "v"(a), "v"(b), "v"(c))
#define PKH_ACC_LO(d, m, s) \
  asm("v_pk_fma_f16 %0, %1, %2, %0 op_sel:[0,0,0] op_sel_hi:[1,0,1]" \
      : "+v"(d) : "v"(m), "v"(s))
#define PKH_ACC_HI(d, m, s) \
  asm("v_pk_fma_f16 %0, %1, %2, %0 op_sel:[0,1,0] op_sel_hi:[1,1,1]" \
      : "+v"(d) : "v"(m), "v"(s))
#define PKH_MUL_LO(d, m, s) \
  asm("v_pk_mul_f16 %0, %1, %2 op_sel:[0,0] op_sel_hi:[1,0]" \
      : "=v"(d) : "v"(m), "v"(s))
// f16 (bits[15:0] of u) -> f32, opaque to the optimizer
#define CVT_H2F(f, u) asm("v_cvt_f32_f16 %0, %1" : "=v"(f) : "v"(u))

__device__ __forceinline__ unsigned short f2h_bits(float f) {
    union { _Float16 h; unsigned short u; } c;
    c.h = (_Float16)f;
    return c.u;
}
__device__ __forceinline__ float hlo(unsigned u) {
    union { unsigned short s; _Float16 h; } c;
    c.s = (unsigned short)(u & 0xffff);
    return (float)c.h;
}
__device__ __forceinline__ float hhi(unsigned u) {
    union { unsigned short s; _Float16 h; } c;
    c.s = (unsigned short)(u >> 16);
    return (float)c.h;
}

// dst(5x10) = src(5x10) * M(site); M blended row-pair at a time from LDS.
__device__ __forceinline__ void site_step(const unsigned* __restrict__ ws,
                                          const unsigned x2,
                                          const unsigned (&src)[5][5],
                                          unsigned (&dst)[5][5]) {
#pragma unroll
    for (int ip = 0; ip < 5; ++ip) {
        unsigned m[10];   // m[q]: M[2ip][pair q]; m[5+q]: M[2ip+1][pair q]
        const uint4* w4 = (const uint4*)(ws + ip * 20);
#pragma unroll
        for (int t = 0; t < 5; ++t) {
            const uint4 w = w4[t];
            PKH_FMA(m[2 * t],     w.y, x2, w.x);
            PKH_FMA(m[2 * t + 1], w.w, x2, w.z);
        }
#pragma unroll
        for (int r = 0; r < 5; ++r) {
            if (ip == 0) {
#pragma unroll
                for (int q = 0; q < 5; ++q) PKH_MUL_LO(dst[r][q], m[q], src[r][0]);
            } else {
#pragma unroll
                for (int q = 0; q < 5; ++q) PKH_ACC_LO(dst[r][q], m[q], src[r][ip]);
            }
#pragma unroll
            for (int q = 0; q < 5; ++q) PKH_ACC_HI(dst[r][q], m[5 + q], src[r][ip]);
        }
    }
}

// ---------------- K1: f16 chain, 2 lanes per sample, L=8 ------------------
__global__ __launch_bounds__(256, 4) void chunk_kernel(
    const float* __restrict__ x, const float* __restrict__ cores,
    unsigned* __restrict__ pbuf, float* __restrict__ lbuf) {
    __shared__ unsigned s_w[LCH * 100];  // per-site f16 {A,D} dwords
    __shared__ float    s_x[128 * 9];    // x slice, stride 9

    const int c   = blockIdx.y;
    const int n0  = 1 + c * LCH;
    const int n1  = min(n0 + LCH, Nn);
    const int ns  = n1 - n0;
    const int tid = (int)threadIdx.x;
    const int b0  = (int)blockIdx.x * 128;

    for (int e = tid; e < ns * 50; e += 256) {
        const int k = e / 50, s = e - k * 50;
        const int i = s / 5, q = s - i * 5;
        const float* g = cores + (size_t)(n0 - 1 + k) * 200 + i * 20 + 2 * q;
        const float a0 = g[0], a1 = g[1], bb0 = g[10], bb1 = g[11];
        const unsigned A = ((unsigned)f2h_bits(2.f * a1) << 16) | f2h_bits(2.f * a0);
        const unsigned D = ((unsigned)f2h_bits(2.f * (bb1 - a1)) << 16) |
                           f2h_bits(2.f * (bb0 - a0));
        s_w[k * 100 + 2 * s]     = A;
        s_w[k * 100 + 2 * s + 1] = D;
    }
    for (int e = tid; e < 128 * 8; e += 256) {
        const int bl = e >> 3, k = e & 7;
        if (k < ns) s_x[bl * 9 + k] = x[(size_t)(b0 + bl) * Nn + n0 + k];
    }
    __syncthreads();

    const int h = tid & 1;
    const int u = tid >> 1;
    const int b = b0 + u;
    const float* __restrict__ xs = s_x + u * 9;

    unsigned p[5][5], q2[5][5];
    {   // first site: P = 2*M (rows 5h..5h+4)
        const unsigned short xb = f2h_bits(xs[0]);
        const unsigned x2 = ((unsigned)xb << 16) | xb;
#pragma unroll
        for (int r = 0; r < 5; ++r)
#pragma unroll
            for (int q = 0; q < 5; ++q) {
                const unsigned A = s_w[(5 * h + r) * 10 + 2 * q];
                const unsigned D = s_w[(5 * h + r) * 10 + 2 * q + 1];
                PKH_FMA(p[r][q], D, x2, A);
            }
    }
    int k = 1;
    while (k + 1 < ns) {
        {
            const unsigned short xb = f2h_bits(xs[k]);
            site_step(s_w + k * 100, ((unsigned)xb << 16) | xb, p, q2);
        }
        {
            const unsigned short xb = f2h_bits(xs[k + 1]);
            site_step(s_w + (k + 1) * 100, ((unsigned)xb << 16) | xb, q2, p);
        }
        k += 2;
    }
    if (k < ns) {
        const unsigned short xb = f2h_bits(xs[k]);
        site_step(s_w + k * 100, ((unsigned)xb << 16) | xb, p, q2);
#pragma unroll
        for (int r = 0; r < 5; ++r)
#pragma unroll
            for (int q = 0; q < 5; ++q) p[r][q] = q2[r][q];
    }

    float ss = 0.f;
#pragma unroll
    for (int r = 0; r < 5; ++r)
#pragma unroll
        for (int q = 0; q < 5; ++q) {
            const float lo = hlo(p[r][q]), hi = hhi(p[r][q]);
            ss = fmaf(lo, lo, ss);
            ss = fmaf(hi, hi, ss);
        }
    ss += __shfl_xor(ss, 1);
    ss = fmaxf(ss, 1e-30f);
    const float rin = rsqrtf(ss);
    if (h == 0)
        lbuf[(size_t)c * Bsz + b] = 0.5f * __logf(ss) - (float)ns * 0.69314718056f;

    unsigned* dst = pbuf + ((size_t)c * Bsz + b) * 50;
#pragma unroll
    for (int r = 0; r < 5; ++r)
#pragma unroll
        for (int q = 0; q < 5; ++q) {
            const float lo = hlo(p[r][q]) * rin;
            const float hi = hhi(p[r][q]) * rin;
            dst[(5 * h + r) * 5 + q] =
                ((unsigned)f2h_bits(hi) << 16) | f2h_bits(lo);
        }
}

// -------- K2: combine, depth-15 DMA ring (16 slots) + 2-stage pipeline ----
__global__ __launch_bounds__(64, 1) void combine_kernel(
    const float* __restrict__ x, const float* __restrict__ core0,
    const float* __restrict__ cls, const unsigned* __restrict__ pbuf,
    const float* __restrict__ lbuf, float* __restrict__ out, int C) {
    __shared__ __align__(16) unsigned ring[16][256];

    const int tid   = (int)threadIdx.x;
    const int j     = tid & 15;
    const int jj    = (j < 10) ? j : 9;
    const int gbase = tid & 48;
    const int sl    = tid >> 4;               // sample slot 0..3
    const int b     = (int)blockIdx.x * 4 + sl;
    const int qoff  = jj >> 1;
    const unsigned sh = (unsigned)(jj & 1) * 16;

    // ---- v init + lbuf pre-sum (all global loads BEFORE staging) ----
    float v[10];
    const float x0 = x[(size_t)b * Nn];
#pragma unroll
    for (int i = 0; i < 10; ++i) {
        const float c0 = core0[i], c1 = core0[10 + i];
        v[i] = fmaf(x0, c1 - c0, c0);
    }
    float llog = 0.f;
    for (int cc = j; cc < C; cc += 16)
        llog += lbuf[(size_t)cc * Bsz + b];
    llog += __shfl_xor(llog, 1);
    llog += __shfl_xor(llog, 2);
    llog += __shfl_xor(llog, 4);
    llog += __shfl_xor(llog, 8);

    // ---- staging: lane stages dwords [l*4, l*4+4) of the wave's 200 ----
    const int flat = (tid * 4 <= 196) ? tid * 4 : 196;
    const unsigned* gsrc0 = pbuf + (size_t)blockIdx.x * 200 + flat;
    const size_t cstride = (size_t)Bsz * 50;

#define STAGE(cc)                                                          \
    __builtin_amdgcn_global_load_lds(                                      \
        (const __attribute__((address_space(1))) unsigned*)(gsrc0 +        \
            (size_t)(cc) * cstride),                                       \
        (__attribute__((address_space(3))) unsigned*)&ring[(cc) & 15][0],  \
        16, 0, 0)

#pragma unroll
    for (int d = 0; d < 15; ++d) STAGE(d);    // prologue: 15 in flight

    const int lbase = sl * 50 + qoff;

#define CONSUME(UARR, cc)                                                  \
    {                                                                      \
        float acc = 0.f;                                                   \
        _Pragma("unroll")                                                  \
        for (int i = 0; i < 10; ++i) {                                     \
            float wv;                                                      \
            CVT_H2F(wv, UARR[i]);                                          \
            acc = fmaf(v[i], wv, acc);                                     \
        }                                                                  \
        if (j >= 10) acc = 0.f;                                            \
        if (((cc) & 7) == 7 || (cc) == C - 1) {                            \
            float s = acc * acc;                                           \
            s += __shfl_xor(s, 1);                                         \
            s += __shfl_xor(s, 2);                                         \
            s += __shfl_xor(s, 4);                                         \
            s += __shfl_xor(s, 8);                                         \
            s = fmaxf(s, 1e-30f);                                          \
            llog += 0.5f * __logf(s);                                      \
            acc *= rsqrtf(s);                                              \
        }                                                                  \
        _Pragma("unroll")                                                  \
        for (int i = 0; i < 10; ++i) v[i] = __shfl(acc, gbase + i);        \
    }

#define RINGREAD(UARR, cc)                                                 \
    {                                                                      \
        const unsigned* rp = &ring[(cc) & 15][lbase];                      \
        _Pragma("unroll")                                                  \
        for (int i = 0; i < 10; ++i) UARR[i] = rp[i * 5] >> sh;            \
    }

    unsigned uA[10], uB[10];
    asm volatile("s_waitcnt vmcnt(14)" ::: "memory");  // slot 0 arrived
    RINGREAD(uA, 0);

    for (int c = 0; c < C; c += 2) {
        // even: compute chunk c from uA; prefetch c+1's LDS reads into uB
        if (c + 1 < C) {
            if (c + 14 < C) {
                asm volatile("s_waitcnt vmcnt(13)" ::: "memory");
            } else {
                asm volatile("s_waitcnt vmcnt(0)" ::: "memory");
            }
            RINGREAD(uB, c + 1);
        }
        CONSUME(uA, c);
        if (c + 15 < C) STAGE(c + 15);   // slot (c-1)&15, read 2 iters ago
        if (c + 1 >= C) break;

        // odd: compute chunk c+1 from uB; prefetch c+2 into uA
        if (c + 2 < C) {
            if (c + 15 < C) {
                asm volatile("s_waitcnt vmcnt(13)" ::: "memory");
            } else {
                asm volatile("s_waitcnt vmcnt(0)" ::: "memory");
            }
            RINGREAD(uA, c + 2);
        }
        CONSUME(uB, c + 1);
        if (c + 16 < C) STAGE(c + 16);   // slot c&15, read 2 iters ago
    }
#undef RINGREAD
#undef CONSUME
#undef STAGE

    if (j < 10) {
        float acc = llog;
#pragma unroll
        for (int i = 0; i < 10; ++i) acc = fmaf(v[i], cls[j * 10 + i], acc);
        out[(size_t)b * 10 + j] = acc;
    }
}

// ---------------- launch ----------------
extern "C" void kernel_launch(void* const* d_in, const int* in_sizes, int n_in,
                              void* d_out, int out_size, void* d_ws, size_t ws_size,
                              hipStream_t stream) {
    const float* x     = (const float*)d_in[0];
    const float* core0 = (const float*)d_in[1];
    const float* cores = (const float*)d_in[2];
    const float* cls   = (const float*)d_in[3];
    float* out = (float*)d_out;

    const int C = NCH;                          // 98
    unsigned* pbuf = (unsigned*)d_ws;           // C*Bsz*50 dwords = 40.1 MB
    float*    lbuf = (float*)(pbuf + (size_t)C * Bsz * 50);

    hipLaunchKernelGGL(chunk_kernel, dim3(Bsz / 128, C), dim3(256),
                       0, stream, x, cores, pbuf, lbuf);
    hipLaunchKernelGGL(combine_kernel, dim3(Bsz / 4), dim3(64),
                       0, stream, x, core0, cls, pbuf, lbuf, out, C);
}

// Round 22
// 72.585 us; speedup vs baseline: 1.1078x; 1.1078x over previous
//
#include <hip/hip_runtime.h>

// MPS classifier: logits[b,o] = (v/||v||)·cls[o] + log||v||,
//   v = head0(b) · M_1(b) · ... · M_783(b),  M_n = A_n + x[b,n]*(B_n - A_n).
// Chain associative; normalizations telescope.
//
// K1 (chunk_kernel): f16 chain, 2 lanes/sample, L=16 (C=49), IN-PLACE row
//   update with ONE persistent [5][5] array (allocator-collapse hypothesis:
//   two ping-pong arrays as asm-tied operands trigger VGPR-32 demotion).
//   r21's version had the blend indexing WRONG (uint4 w4[t] spans flat
//   pairs 2t,2t+1 of the ROW-PAIR and crosses rows at t=2); this uses the
//   flat Mf[ip*10+f] layout exactly like r18's proven site_step, consumed
//   as row i pair q -> Mf[(i>>1)*10 + (i&1)*5 + q].
// K2 (combine_kernel, == r18 verbatim, proven ~13us @ C=49, race-clean):
//   depth-7 DMA ring on 8 LDS slots, counted s_waitcnt vmcnt(6), lbuf
//   pre-summed before staging. 512 x 64 blocks.

constexpr int Bsz = 2048;
constexpr int Nn  = 784;
constexpr int NS  = 783;
constexpr int LCH = 16;     // sites per chunk
constexpr int NCH = (NS + LCH - 1) / LCH;   // 49 chunks

// packed-f16 VOP3P on raw i32 registers (semantics proven r9-r20).
#define PKH_FMA(d, a, b, c) \
  asm("v_pk_fma_f16 %0, %1, %2, %3" : "=v"(d) : "v"(a), "v"(b), "v"(c))
#define PKH_ACC_LO(d, m, s) \
  asm("v_pk_fma_f16 %0, %1, %2, %0 op_sel:[0,0,0] op_sel_hi:[1,0,1]" \
      : "+v"(d) : "v"(m), "v"(s))
#define PKH_ACC_HI(d, m, s) \
  asm("v_pk_fma_f16 %0, %1, %2, %0 op_sel:[0,1,0] op_sel_hi:[1,1,1]" \
      : "+v"(d) : "v"(m), "v"(s))
#define PKH_MUL_LO(d, m, s) \
  asm("v_pk_mul_f16 %0, %1, %2 op_sel:[0,0] op_sel_hi:[1,0]" \
      : "=v"(d) : "v"(m), "v"(s))
// f16 (bits[15:0] of u) -> f32, opaque to the optimizer
#define CVT_H2F(f, u) asm("v_cvt_f32_f16 %0, %1" : "=v"(f) : "v"(u))

__device__ __forceinline__ unsigned short f2h_bits(float f) {
    union { _Float16 h; unsigned short u; } c;
    c.h = (_Float16)f;
    return c.u;
}
__device__ __forceinline__ float hlo(unsigned u) {
    union { unsigned short s; _Float16 h; } c;
    c.s = (unsigned short)(u & 0xffff);
    return (float)c.h;
}
__device__ __forceinline__ float hhi(unsigned u) {
    union { unsigned short s; _Float16 h; } c;
    c.s = (unsigned short)(u >> 16);
    return (float)c.h;
}

// ---------------- K1: f16 chain, in-place, 2 lanes/sample, L=16 -----------
__global__ __launch_bounds__(256, 4) void chunk_kernel(
    const float* __restrict__ x, const float* __restrict__ cores,
    unsigned* __restrict__ pbuf, float* __restrict__ lbuf) {
    __shared__ unsigned s_w[LCH * 100];  // per-site f16 {A,D} dwords
    __shared__ float    s_x[128 * 17];   // x slice, stride 17

    const int c   = blockIdx.y;
    const int n0  = 1 + c * LCH;
    const int n1  = min(n0 + LCH, Nn);
    const int ns  = n1 - n0;
    const int tid = (int)threadIdx.x;
    const int b0  = (int)blockIdx.x * 128;

    // stage + convert weights (fused repack): pair e=(k,s), s=(i*5+q)
    for (int e = tid; e < ns * 50; e += 256) {
        const int k = e / 50, s = e - k * 50;
        const int i = s / 5, q = s - i * 5;
        const float* g = cores + (size_t)(n0 - 1 + k) * 200 + i * 20 + 2 * q;
        const float a0 = g[0], a1 = g[1], bb0 = g[10], bb1 = g[11];
        const unsigned A = ((unsigned)f2h_bits(2.f * a1) << 16) | f2h_bits(2.f * a0);
        const unsigned D = ((unsigned)f2h_bits(2.f * (bb1 - a1)) << 16) |
                           f2h_bits(2.f * (bb0 - a0));
        s_w[k * 100 + 2 * s]     = A;
        s_w[k * 100 + 2 * s + 1] = D;
    }
    for (int e = tid; e < 128 * 16; e += 256) {
        const int bl = e >> 4, k = e & 15;
        if (k < ns) s_x[bl * 17 + k] = x[(size_t)(b0 + bl) * Nn + n0 + k];
    }
    __syncthreads();

    const int h = tid & 1;              // row-half owner
    const int u = tid >> 1;             // sample slot 0..127
    const int b = b0 + u;
    const float* __restrict__ xs = s_x + u * 17;

    unsigned p[5][5];                   // the ONLY chain-carried state
    {   // first site: P = 2*M (rows 5h..5h+4)
        const unsigned short xb = f2h_bits(xs[0]);
        const unsigned x2 = ((unsigned)xb << 16) | xb;
#pragma unroll
        for (int r = 0; r < 5; ++r)
#pragma unroll
            for (int q = 0; q < 5; ++q) {
                const unsigned A = s_w[(5 * h + r) * 10 + 2 * q];
                const unsigned D = s_w[(5 * h + r) * 10 + 2 * q + 1];
                PKH_FMA(p[r][q], D, x2, A);
            }
    }

    for (int k = 1; k < ns; ++k) {
        const unsigned short xb = f2h_bits(xs[k]);
        const unsigned x2 = ((unsigned)xb << 16) | xb;
        const unsigned* ws = s_w + k * 100;

        // blend full M: Mf[ip*10 + f] = flat pair f of row-pair ip
        //   (flat pairs 0..4 -> row 2ip pairs 0..4; 5..9 -> row 2ip+1)
        unsigned Mf[50];
#pragma unroll
        for (int ip = 0; ip < 5; ++ip) {
            const uint4* w4 = (const uint4*)(ws + ip * 20);
#pragma unroll
            for (int t = 0; t < 5; ++t) {
                const uint4 w = w4[t];
                PKH_FMA(Mf[ip * 10 + 2 * t],     w.y, x2, w.x);
                PKH_FMA(Mf[ip * 10 + 2 * t + 1], w.w, x2, w.z);
            }
        }

        // in-place: p[r] = p[r] · M (row fully read before overwrite).
        // row i, pair q lives at Mf[(i>>1)*10 + (i&1)*5 + q].
#pragma unroll
        for (int r = 0; r < 5; ++r) {
            unsigned acc[5];
#pragma unroll
            for (int q = 0; q < 5; ++q)
                PKH_MUL_LO(acc[q], Mf[q], p[r][0]);            // row 0
#pragma unroll
            for (int q = 0; q < 5; ++q)
                PKH_ACC_HI(acc[q], Mf[5 + q], p[r][0]);        // row 1
#pragma unroll
            for (int ip = 1; ip < 5; ++ip) {
#pragma unroll
                for (int q = 0; q < 5; ++q)
                    PKH_ACC_LO(acc[q], Mf[ip * 10 + q], p[r][ip]);      // row 2ip
#pragma unroll
                for (int q = 0; q < 5; ++q)
                    PKH_ACC_HI(acc[q], Mf[ip * 10 + 5 + q], p[r][ip]);  // row 2ip+1
            }
#pragma unroll
            for (int q = 0; q < 5; ++q) p[r][q] = acc[q];
        }
    }

    // Frobenius renorm (f32 accumulate, pair-reduce across the 2 lanes);
    // correct the 2^ns pre-scale in lbuf.
    float ss = 0.f;
#pragma unroll
    for (int r = 0; r < 5; ++r)
#pragma unroll
        for (int q = 0; q < 5; ++q) {
            const float lo = hlo(p[r][q]), hi = hhi(p[r][q]);
            ss = fmaf(lo, lo, ss);
            ss = fmaf(hi, hi, ss);
        }
    ss += __shfl_xor(ss, 1);
    ss = fmaxf(ss, 1e-30f);
    const float rin = rsqrtf(ss);
    if (h == 0)
        lbuf[(size_t)c * Bsz + b] = 0.5f * __logf(ss) - (float)ns * 0.69314718056f;

    // store packed f16 dwords: pbuf[(c*Bsz+b)*50 + (5h+r)*5 + q]
    unsigned* dst = pbuf + ((size_t)c * Bsz + b) * 50;
#pragma unroll
    for (int r = 0; r < 5; ++r)
#pragma unroll
        for (int q = 0; q < 5; ++q) {
            const float lo = hlo(p[r][q]) * rin;
            const float hi = hhi(p[r][q]) * rin;
            dst[(5 * h + r) * 5 + q] =
                ((unsigned)f2h_bits(hi) << 16) | f2h_bits(lo);
        }
}

// ---------------- K2: combine via explicit LDS pipeline (depth-7) ---------
__global__ __launch_bounds__(64, 1) void combine_kernel(
    const float* __restrict__ x, const float* __restrict__ core0,
    const float* __restrict__ cls, const unsigned* __restrict__ pbuf,
    const float* __restrict__ lbuf, float* __restrict__ out, int C) {
    __shared__ __align__(16) unsigned ring[8][256];

    const int tid   = (int)threadIdx.x;
    const int j     = tid & 15;
    const int jj    = (j < 10) ? j : 9;
    const int gbase = tid & 48;
    const int sl    = tid >> 4;               // sample slot 0..3
    const int b     = (int)blockIdx.x * 4 + sl;
    const int qoff  = jj >> 1;
    const unsigned sh = (unsigned)(jj & 1) * 16;

    // ---- v init + lbuf pre-sum (all global loads BEFORE staging) ----
    float v[10];
    const float x0 = x[(size_t)b * Nn];
#pragma unroll
    for (int i = 0; i < 10; ++i) {
        const float c0 = core0[i], c1 = core0[10 + i];
        v[i] = fmaf(x0, c1 - c0, c0);
    }
    float llog = 0.f;
    for (int cc = j; cc < C; cc += 16)
        llog += lbuf[(size_t)cc * Bsz + b];
    llog += __shfl_xor(llog, 1);
    llog += __shfl_xor(llog, 2);
    llog += __shfl_xor(llog, 4);
    llog += __shfl_xor(llog, 8);

    // ---- staging: lane stages dwords [l*4, l*4+4) of the wave's 200 ----
    const int flat = (tid * 4 <= 196) ? tid * 4 : 196;
    const unsigned* gsrc0 = pbuf + (size_t)blockIdx.x * 200 + flat;
    const size_t cstride = (size_t)Bsz * 50;

#define STAGE(cc)                                                          \
    __builtin_amdgcn_global_load_lds(                                      \
        (const __attribute__((address_space(1))) unsigned*)(gsrc0 +        \
            (size_t)(cc) * cstride),                                       \
        (__attribute__((address_space(3))) unsigned*)&ring[(cc) & 7][0],   \
        16, 0, 0)

#pragma unroll
    for (int d = 0; d < 7; ++d) STAGE(d);     // prologue: 7 in flight

    const int lbase = sl * 50 + qoff;
    for (int c = 0; c < C; ++c) {
        const int d = c & 7;
        if (c + 7 <= C - 1) {
            asm volatile("s_waitcnt vmcnt(6)" ::: "memory");
        } else {
            asm volatile("s_waitcnt vmcnt(0)" ::: "memory");
        }
        __builtin_amdgcn_sched_barrier(0);

        float acc = 0.f;
#pragma unroll
        for (int i = 0; i < 10; ++i) {
            unsigned ud = ring[d][lbase + i * 5] >> sh;
            float wv;
            CVT_H2F(wv, ud);
            acc = fmaf(v[i], wv, acc);
        }
        if (j >= 10) acc = 0.f;
        if ((c & 7) == 7 || c == C - 1) {     // deferred renorm
            float s = acc * acc;
            s += __shfl_xor(s, 1);
            s += __shfl_xor(s, 2);
            s += __shfl_xor(s, 4);
            s += __shfl_xor(s, 8);
            s = fmaxf(s, 1e-30f);
            llog += 0.5f * __logf(s);
            acc *= rsqrtf(s);
        }
#pragma unroll
        for (int i = 0; i < 10; ++i) v[i] = __shfl(acc, gbase + i);

        // refill: targets slot (c+7)&7 = (c-1)&7, consumed LAST iteration
        if (c + 7 < C) STAGE(c + 7);
    }
#undef STAGE

    if (j < 10) {
        float acc = llog;
#pragma unroll
        for (int i = 0; i < 10; ++i) acc = fmaf(v[i], cls[j * 10 + i], acc);
        out[(size_t)b * 10 + j] = acc;
    }
}

// ---------------- launch ----------------
extern "C" void kernel_launch(void* const* d_in, const int* in_sizes, int n_in,
                              void* d_out, int out_size, void* d_ws, size_t ws_size,
                              hipStream_t stream) {
    const float* x     = (const float*)d_in[0];
    const float* core0 = (const float*)d_in[1];
    const float* cores = (const float*)d_in[2];
    const float* cls   = (const float*)d_in[3];
    float* out = (float*)d_out;

    const int C = NCH;                          // 49
    unsigned* pbuf = (unsigned*)d_ws;           // C*Bsz*50 dwords = 20.1 MB
    float*    lbuf = (float*)(pbuf + (size_t)C * Bsz * 50);

    hipLaunchKernelGGL(chunk_kernel, dim3(Bsz / 128, C), dim3(256),
                       0, stream, x, cores, pbuf, lbuf);
    hipLaunchKernelGGL(combine_kernel, dim3(Bsz / 4), dim3(64),
                       0, stream, x, core0, cls, pbuf, lbuf, out, C);
}